// Round 1
// baseline (2241.349 us; speedup 1.0000x reference)
//
#include <hip/hip_runtime.h>

constexpr int NN = 50000;          // nodes
constexpr int NE = 800000;         // edges
constexpr int C1 = 128;            // in/hidden channels
constexpr int C2 = 64;             // out channels

// ---------------- degree / normalization ----------------
__global__ void deg_kernel(const int* __restrict__ dst, float* __restrict__ deg) {
    int e = blockIdx.x * 256 + threadIdx.x;
    if (e < NE) atomicAdd(&deg[dst[e]], 1.0f);
}

__global__ void dinv_kernel(float* __restrict__ deg) {
    int n = blockIdx.x * 256 + threadIdx.x;
    if (n < NN) deg[n] = rsqrtf(deg[n] + 1.0f);   // +1 self loop; always > 0
}

// ---------------- matmul 1: g1 = dinv * (x @ W1), x[N,128], W1[128,128] ----------------
__global__ __launch_bounds__(256) void mm1_kernel(const float* __restrict__ x,
                                                  const float* __restrict__ W,
                                                  const float* __restrict__ dinv,
                                                  float* __restrict__ g1) {
    __shared__ float xs[32][128];     // 16 KB
    __shared__ float Wl[64][128];     // 32 KB (half of K at a time)
    const int t = threadIdx.x;
    const int row0 = blockIdx.x * 32;

    // stage 32 rows of x (4096 floats -> 4 float4 per thread)
    #pragma unroll
    for (int i = 0; i < 4; i++) {
        int fi = t + i * 256;             // float4 index in tile (0..1023)
        int r = fi >> 5;                  // 32 float4 per row
        int c4 = fi & 31;
        int row = row0 + r;
        float4 v = (row < NN) ? ((const float4*)x)[(size_t)row * 32 + c4]
                              : make_float4(0.f, 0.f, 0.f, 0.f);
        *(float4*)&xs[r][c4 * 4] = v;
    }

    float acc[4][4];
    #pragma unroll
    for (int a = 0; a < 4; a++)
        #pragma unroll
        for (int b = 0; b < 4; b++) acc[a][b] = 0.f;

    const int cg = t & 31;     // col group: cols 4*cg .. 4*cg+3
    const int rsub = t >> 5;   // 0..7

    for (int kh = 0; kh < 2; kh++) {
        __syncthreads();
        // stage W[kh*64 .. kh*64+63][0..127] : 8192 floats -> 8 float4/thread
        #pragma unroll
        for (int i = 0; i < 8; i++) {
            int fi = t + i * 256;            // 0..2047
            int kk = fi >> 5;
            int cc = fi & 31;
            ((float4*)&Wl[kk][0])[cc] = ((const float4*)W)[(size_t)(kh * 64 + kk) * 32 + cc];
        }
        __syncthreads();
        #pragma unroll
        for (int rt = 0; rt < 4; rt++) {
            int r = rt * 8 + rsub;
            #pragma unroll 8
            for (int k = 0; k < 64; k++) {
                float xv = xs[r][kh * 64 + k];
                float4 wv = *(const float4*)&Wl[k][cg * 4];
                acc[rt][0] += xv * wv.x;
                acc[rt][1] += xv * wv.y;
                acc[rt][2] += xv * wv.z;
                acc[rt][3] += xv * wv.w;
            }
        }
    }

    #pragma unroll
    for (int rt = 0; rt < 4; rt++) {
        int row = row0 + rt * 8 + rsub;
        if (row < NN) {
            float s = dinv[row];
            ((float4*)g1)[(size_t)row * 32 + cg] =
                make_float4(acc[rt][0] * s, acc[rt][1] * s, acc[rt][2] * s, acc[rt][3] * s);
        }
    }
}

// ---------------- matmul 2: g2 = dinv * (x2 @ W2), x2[N,128], W2[128,64] ----------------
__global__ __launch_bounds__(256) void mm2_kernel(const float* __restrict__ x2,
                                                  const float* __restrict__ W,
                                                  const float* __restrict__ dinv,
                                                  float* __restrict__ g2) {
    __shared__ float xs[32][132];     // padded: 4 distinct rows/wave would hit same bank
    __shared__ float Wl[128][64];     // 32 KB, all of W2
    const int t = threadIdx.x;
    const int row0 = blockIdx.x * 32;

    // stage all of W2: 8192 floats -> 8 float4/thread
    #pragma unroll
    for (int i = 0; i < 8; i++) {
        int fi = t + i * 256;
        ((float4*)Wl)[fi] = ((const float4*)W)[fi];
    }
    // stage 32 rows of x2
    #pragma unroll
    for (int i = 0; i < 4; i++) {
        int fi = t + i * 256;
        int r = fi >> 5;
        int c4 = fi & 31;
        int row = row0 + r;
        float4 v = (row < NN) ? ((const float4*)x2)[(size_t)row * 32 + c4]
                              : make_float4(0.f, 0.f, 0.f, 0.f);
        *(float4*)&xs[r][c4 * 4] = v;
    }
    __syncthreads();

    const int cg = t & 15;     // cols 4*cg..4*cg+3 of 64
    const int rsub = t >> 4;   // 0..15
    float acc[2][4];
    #pragma unroll
    for (int a = 0; a < 2; a++)
        #pragma unroll
        for (int b = 0; b < 4; b++) acc[a][b] = 0.f;

    #pragma unroll
    for (int rt = 0; rt < 2; rt++) {
        int r = rt * 16 + rsub;
        #pragma unroll 8
        for (int k = 0; k < 128; k++) {
            float xv = xs[r][k];
            float4 wv = *(const float4*)&Wl[k][cg * 4];
            acc[rt][0] += xv * wv.x;
            acc[rt][1] += xv * wv.y;
            acc[rt][2] += xv * wv.z;
            acc[rt][3] += xv * wv.w;
        }
    }
    #pragma unroll
    for (int rt = 0; rt < 2; rt++) {
        int row = row0 + rt * 16 + rsub;
        if (row < NN) {
            float s = dinv[row];
            ((float4*)g2)[(size_t)row * 16 + cg] =
                make_float4(acc[rt][0] * s, acc[rt][1] * s, acc[rt][2] * s, acc[rt][3] * s);
        }
    }
}

// ---------------- edge scatter: agg[dst] += g[src], one float4 per thread ----------------
template <int CV_SHIFT>   // log2(C/4): 5 for C=128, 4 for C=64
__global__ void scatter_kernel(const int* __restrict__ src, const int* __restrict__ dst,
                               const float* __restrict__ g, float* __restrict__ agg) {
    int idx = blockIdx.x * 256 + threadIdx.x;   // over NE << CV_SHIFT, exact multiple of 256
    int e = idx >> CV_SHIFT;
    int c = idx & ((1 << CV_SHIFT) - 1);
    int s = src[e];
    int d = dst[e];
    float4 v = ((const float4*)g)[((size_t)s << CV_SHIFT) + c];
    float* p = agg + (((size_t)d << CV_SHIFT) + c) * 4;
    atomicAdd(p + 0, v.x);
    atomicAdd(p + 1, v.y);
    atomicAdd(p + 2, v.z);
    atomicAdd(p + 3, v.w);
}

// ---------------- epilogue 1: x2 = relu(dinv*(agg1+g1)+b1), in place over agg1 ----------------
__global__ void epi1_kernel(float* __restrict__ agg1, const float* __restrict__ g1,
                            const float* __restrict__ dinv, const float* __restrict__ b1) {
    int idx = blockIdx.x * 256 + threadIdx.x;   // over NN*32 float4s = 1.6M, exact
    int row = idx >> 5;
    int c = idx & 31;
    float s = dinv[row];
    float4 a = ((float4*)agg1)[idx];
    float4 g = ((const float4*)g1)[idx];
    float4 bb = ((const float4*)b1)[c];
    float4 o;
    o.x = fmaxf(s * (a.x + g.x) + bb.x, 0.f);
    o.y = fmaxf(s * (a.y + g.y) + bb.y, 0.f);
    o.z = fmaxf(s * (a.z + g.z) + bb.z, 0.f);
    o.w = fmaxf(s * (a.w + g.w) + bb.w, 0.f);
    ((float4*)agg1)[idx] = o;
}

// ---------------- epilogue 2: out = dinv*(out+g2)+b2, in place over d_out ----------------
__global__ void epi2_kernel(float* __restrict__ out, const float* __restrict__ g2,
                            const float* __restrict__ dinv, const float* __restrict__ b2) {
    int idx = blockIdx.x * 256 + threadIdx.x;   // over NN*16 float4s = 800K, exact
    int row = idx >> 4;
    int c = idx & 15;
    float s = dinv[row];
    float4 a = ((float4*)out)[idx];
    float4 g = ((const float4*)g2)[idx];
    float4 bb = ((const float4*)b2)[c];
    float4 o;
    o.x = s * (a.x + g.x) + bb.x;
    o.y = s * (a.y + g.y) + bb.y;
    o.z = s * (a.z + g.z) + bb.z;
    o.w = s * (a.w + g.w) + bb.w;
    ((float4*)out)[idx] = o;
}

extern "C" void kernel_launch(void* const* d_in, const int* in_sizes, int n_in,
                              void* d_out, int out_size, void* d_ws, size_t ws_size,
                              hipStream_t stream) {
    const float* x  = (const float*)d_in[0];
    const int* edges = (const int*)d_in[1];     // [2, NE] row-major int32
    const float* W1 = (const float*)d_in[2];
    const float* b1 = (const float*)d_in[3];
    const float* W2 = (const float*)d_in[4];
    const float* b2 = (const float*)d_in[5];
    const int* src = edges;
    const int* dst = edges + NE;

    float* w = (float*)d_ws;
    float* dinv = w;                         // 50000 (used first as deg)
    float* g1   = w + 50048;                 // [N,128]
    float* agg1 = g1 + (size_t)NN * C1;      // [N,128], becomes x2 in place
    float* g2   = agg1 + (size_t)NN * C1;    // [N,64]
    float* out  = (float*)d_out;             // [N,64], also layer-2 accumulator

    hipMemsetAsync(dinv, 0, (size_t)NN * sizeof(float), stream);
    hipMemsetAsync(agg1, 0, (size_t)NN * C1 * sizeof(float), stream);
    hipMemsetAsync(out,  0, (size_t)NN * C2 * sizeof(float), stream);

    deg_kernel<<<(NE + 255) / 256, 256, 0, stream>>>(dst, dinv);
    dinv_kernel<<<(NN + 255) / 256, 256, 0, stream>>>(dinv);

    mm1_kernel<<<(NN + 31) / 32, 256, 0, stream>>>(x, W1, dinv, g1);
    scatter_kernel<5><<<(NE * 32) / 256, 256, 0, stream>>>(src, dst, g1, agg1);
    epi1_kernel<<<(NN * 32) / 256, 256, 0, stream>>>(agg1, g1, dinv, b1);

    mm2_kernel<<<(NN + 31) / 32, 256, 0, stream>>>(agg1, W2, dinv, g2);
    scatter_kernel<4><<<(NE * 16) / 256, 256, 0, stream>>>(src, dst, g2, out);
    epi2_kernel<<<(NN * 16) / 256, 256, 0, stream>>>(out, g2, dinv, b2);
}

// Round 2
// 344.891 us; speedup vs baseline: 6.4987x; 6.4987x over previous
//
#include <hip/hip_runtime.h>

constexpr int NN = 50000;          // nodes
constexpr int NE = 800000;         // edges
constexpr int C1 = 128;            // in/hidden channels
constexpr int C2 = 64;             // out channels
constexpr int NB = (NN + 255) / 256;   // 196 scan blocks

// ---------------- CSR build: histogram by dst ----------------
__global__ void hist_kernel(const int* __restrict__ dst, int* __restrict__ cnt) {
    int e = blockIdx.x * 256 + threadIdx.x;
    if (e < NE) atomicAdd(&cnt[dst[e]], 1);
}

// per-block exclusive scan of cnt -> off, block totals -> bsum
__global__ void scan1_kernel(const int* __restrict__ cnt, int* __restrict__ off,
                             int* __restrict__ bsum) {
    __shared__ int s[256];
    int i = blockIdx.x * 256 + threadIdx.x;
    int v = (i < NN) ? cnt[i] : 0;
    s[threadIdx.x] = v;
    __syncthreads();
    #pragma unroll
    for (int d = 1; d < 256; d <<= 1) {
        int t = (threadIdx.x >= d) ? s[threadIdx.x - d] : 0;
        __syncthreads();
        s[threadIdx.x] += t;
        __syncthreads();
    }
    if (i < NN) off[i] = s[threadIdx.x] - v;   // exclusive
    if (threadIdx.x == 255) bsum[blockIdx.x] = s[255];
}

// exclusive scan of the block sums (196 elements — one thread is fine)
__global__ void scan2_kernel(int* __restrict__ bsum) {
    if (threadIdx.x == 0 && blockIdx.x == 0) {
        int run = 0;
        for (int b = 0; b < NB; b++) { int v = bsum[b]; bsum[b] = run; run += v; }
    }
}

// add block offsets; init cursor; dinv = rsqrt(deg+1)
__global__ void scan3_kernel(const int* __restrict__ cnt, int* __restrict__ off,
                             const int* __restrict__ bsum, int* __restrict__ cursor,
                             float* __restrict__ dinv) {
    int i = blockIdx.x * 256 + threadIdx.x;
    if (i < NN) {
        int o = off[i] + bsum[blockIdx.x];
        off[i] = o;
        cursor[i] = o;
        dinv[i] = rsqrtf((float)cnt[i] + 1.0f);
    }
}

// placement scatter: esrc[pos] = src  (pos via int atomic on cursor)
__global__ void build_kernel(const int* __restrict__ src, const int* __restrict__ dst,
                             int* __restrict__ cursor, int* __restrict__ esrc) {
    int e = blockIdx.x * 256 + threadIdx.x;
    if (e < NE) {
        int pos = atomicAdd(&cursor[dst[e]], 1);
        esrc[pos] = src[e];
    }
}

// ---------------- matmul 1: g1 = dinv * (x @ W1), x[N,128], W1[128,128] ----------------
__global__ __launch_bounds__(256) void mm1_kernel(const float* __restrict__ x,
                                                  const float* __restrict__ W,
                                                  const float* __restrict__ dinv,
                                                  float* __restrict__ g1) {
    __shared__ float xs[32][128];
    __shared__ float Wl[64][128];
    const int t = threadIdx.x;
    const int row0 = blockIdx.x * 32;

    #pragma unroll
    for (int i = 0; i < 4; i++) {
        int fi = t + i * 256;
        int r = fi >> 5;
        int c4 = fi & 31;
        int row = row0 + r;
        float4 v = (row < NN) ? ((const float4*)x)[(size_t)row * 32 + c4]
                              : make_float4(0.f, 0.f, 0.f, 0.f);
        *(float4*)&xs[r][c4 * 4] = v;
    }

    float acc[4][4];
    #pragma unroll
    for (int a = 0; a < 4; a++)
        #pragma unroll
        for (int b = 0; b < 4; b++) acc[a][b] = 0.f;

    const int cg = t & 31;
    const int rsub = t >> 5;

    for (int kh = 0; kh < 2; kh++) {
        __syncthreads();
        #pragma unroll
        for (int i = 0; i < 8; i++) {
            int fi = t + i * 256;
            int kk = fi >> 5;
            int cc = fi & 31;
            ((float4*)&Wl[kk][0])[cc] = ((const float4*)W)[(size_t)(kh * 64 + kk) * 32 + cc];
        }
        __syncthreads();
        #pragma unroll
        for (int rt = 0; rt < 4; rt++) {
            int r = rt * 8 + rsub;
            #pragma unroll 8
            for (int k = 0; k < 64; k++) {
                float xv = xs[r][kh * 64 + k];
                float4 wv = *(const float4*)&Wl[k][cg * 4];
                acc[rt][0] += xv * wv.x;
                acc[rt][1] += xv * wv.y;
                acc[rt][2] += xv * wv.z;
                acc[rt][3] += xv * wv.w;
            }
        }
    }

    #pragma unroll
    for (int rt = 0; rt < 4; rt++) {
        int row = row0 + rt * 8 + rsub;
        if (row < NN) {
            float s = dinv[row];
            ((float4*)g1)[(size_t)row * 32 + cg] =
                make_float4(acc[rt][0] * s, acc[rt][1] * s, acc[rt][2] * s, acc[rt][3] * s);
        }
    }
}

// ---------------- matmul 2: g2 = dinv * (x2 @ W2), x2[N,128], W2[128,64] ----------------
__global__ __launch_bounds__(256) void mm2_kernel(const float* __restrict__ x2,
                                                  const float* __restrict__ W,
                                                  const float* __restrict__ dinv,
                                                  float* __restrict__ g2) {
    __shared__ float xs[32][132];
    __shared__ float Wl[128][64];
    const int t = threadIdx.x;
    const int row0 = blockIdx.x * 32;

    #pragma unroll
    for (int i = 0; i < 8; i++) {
        int fi = t + i * 256;
        ((float4*)Wl)[fi] = ((const float4*)W)[fi];
    }
    #pragma unroll
    for (int i = 0; i < 4; i++) {
        int fi = t + i * 256;
        int r = fi >> 5;
        int c4 = fi & 31;
        int row = row0 + r;
        float4 v = (row < NN) ? ((const float4*)x2)[(size_t)row * 32 + c4]
                              : make_float4(0.f, 0.f, 0.f, 0.f);
        *(float4*)&xs[r][c4 * 4] = v;
    }
    __syncthreads();

    const int cg = t & 15;
    const int rsub = t >> 4;
    float acc[2][4];
    #pragma unroll
    for (int a = 0; a < 2; a++)
        #pragma unroll
        for (int b = 0; b < 4; b++) acc[a][b] = 0.f;

    #pragma unroll
    for (int rt = 0; rt < 2; rt++) {
        int r = rt * 16 + rsub;
        #pragma unroll 8
        for (int k = 0; k < 128; k++) {
            float xv = xs[r][k];
            float4 wv = *(const float4*)&Wl[k][cg * 4];
            acc[rt][0] += xv * wv.x;
            acc[rt][1] += xv * wv.y;
            acc[rt][2] += xv * wv.z;
            acc[rt][3] += xv * wv.w;
        }
    }
    #pragma unroll
    for (int rt = 0; rt < 2; rt++) {
        int row = row0 + rt * 16 + rsub;
        if (row < NN) {
            float s = dinv[row];
            ((float4*)g2)[(size_t)row * 16 + cg] =
                make_float4(acc[rt][0] * s, acc[rt][1] * s, acc[rt][2] * s, acc[rt][3] * s);
        }
    }
}

// ---------------- gather-aggregate layer 1: one wave per node, float2/lane (128 ch) ----------------
// x2[n] = relu(dinv[n] * (g1[n] + sum_{s in N(n)} g1[s]) + b1)
__global__ __launch_bounds__(256) void gather1_kernel(const float* __restrict__ g1,
                                                      const int* __restrict__ esrc,
                                                      const int* __restrict__ off,
                                                      const int* __restrict__ cnt,
                                                      const float* __restrict__ dinv,
                                                      const float* __restrict__ b1,
                                                      float* __restrict__ x2) {
    int wave = threadIdx.x >> 6;
    int lane = threadIdx.x & 63;
    int n = blockIdx.x * 4 + wave;
    if (n >= NN) return;
    const float2* G = (const float2*)g1;
    float2 acc = G[(size_t)n * 64 + lane];       // self-loop term
    float2 acc2 = make_float2(0.f, 0.f);
    int s0 = off[n];
    int e0 = s0 + cnt[n];
    int i = s0;
    for (; i + 1 < e0; i += 2) {
        int sa = esrc[i];
        int sb = esrc[i + 1];
        float2 va = G[(size_t)sa * 64 + lane];
        float2 vb = G[(size_t)sb * 64 + lane];
        acc.x += va.x; acc.y += va.y;
        acc2.x += vb.x; acc2.y += vb.y;
    }
    if (i < e0) {
        int sa = esrc[i];
        float2 va = G[(size_t)sa * 64 + lane];
        acc.x += va.x; acc.y += va.y;
    }
    acc.x += acc2.x; acc.y += acc2.y;
    float s = dinv[n];
    float2 bb = ((const float2*)b1)[lane];
    float2 o = make_float2(fmaxf(s * acc.x + bb.x, 0.f), fmaxf(s * acc.y + bb.y, 0.f));
    ((float2*)x2)[(size_t)n * 64 + lane] = o;
}

// ---------------- gather-aggregate layer 2: one wave per node, 1 float/lane (64 ch) ----------------
// out[n] = dinv[n] * (g2[n] + sum) + b2
__global__ __launch_bounds__(256) void gather2_kernel(const float* __restrict__ g2,
                                                      const int* __restrict__ esrc,
                                                      const int* __restrict__ off,
                                                      const int* __restrict__ cnt,
                                                      const float* __restrict__ dinv,
                                                      const float* __restrict__ b2,
                                                      float* __restrict__ out) {
    int wave = threadIdx.x >> 6;
    int lane = threadIdx.x & 63;
    int n = blockIdx.x * 4 + wave;
    if (n >= NN) return;
    float acc = g2[(size_t)n * 64 + lane];       // self-loop term
    float acc2 = 0.f;
    int s0 = off[n];
    int e0 = s0 + cnt[n];
    int i = s0;
    for (; i + 1 < e0; i += 2) {
        int sa = esrc[i];
        int sb = esrc[i + 1];
        acc += g2[(size_t)sa * 64 + lane];
        acc2 += g2[(size_t)sb * 64 + lane];
    }
    if (i < e0) acc += g2[(size_t)esrc[i] * 64 + lane];
    acc += acc2;
    out[(size_t)n * 64 + lane] = dinv[n] * acc + b2[lane];
}

extern "C" void kernel_launch(void* const* d_in, const int* in_sizes, int n_in,
                              void* d_out, int out_size, void* d_ws, size_t ws_size,
                              hipStream_t stream) {
    const float* x  = (const float*)d_in[0];
    const int* edges = (const int*)d_in[1];     // [2, NE] int32
    const float* W1 = (const float*)d_in[2];
    const float* b1 = (const float*)d_in[3];
    const float* W2 = (const float*)d_in[4];
    const float* b2 = (const float*)d_in[5];
    const int* src = edges;
    const int* dst = edges + NE;

    // workspace layout (all 16B-aligned: every chunk is a multiple of 16 bytes)
    int* cnt    = (int*)d_ws;            // 50048
    int* off    = cnt + 50048;           // 50048
    int* cursor = off + 50048;           // 50048
    int* bsum   = cursor + 50048;        // 256
    int* esrc   = bsum + 256;            // 800000
    float* dinv = (float*)(esrc + NE);   // 50048
    float* g1   = dinv + 50048;          // [N,128] = 6.4M floats
    float* x2   = g1 + (size_t)NN * C1;  // [N,128] = 6.4M floats
    float* g2   = g1;                    // alias: g1 dead after gather1, mm2 runs later
    float* out  = (float*)d_out;

    hipMemsetAsync(cnt, 0, (size_t)50048 * sizeof(int), stream);

    hist_kernel<<<(NE + 255) / 256, 256, 0, stream>>>(dst, cnt);
    scan1_kernel<<<NB, 256, 0, stream>>>(cnt, off, bsum);
    scan2_kernel<<<1, 64, 0, stream>>>(bsum);
    scan3_kernel<<<NB, 256, 0, stream>>>(cnt, off, bsum, cursor, dinv);
    build_kernel<<<(NE + 255) / 256, 256, 0, stream>>>(src, dst, cursor, esrc);

    mm1_kernel<<<(NN + 31) / 32, 256, 0, stream>>>(x, W1, dinv, g1);
    gather1_kernel<<<(NN + 3) / 4, 256, 0, stream>>>(g1, esrc, off, cnt, dinv, b1, x2);

    mm2_kernel<<<(NN + 31) / 32, 256, 0, stream>>>(x2, W2, dinv, g2);
    gather2_kernel<<<(NN + 3) / 4, 256, 0, stream>>>(g2, esrc, off, cnt, dinv, b2, out);
}

// Round 3
// 302.153 us; speedup vs baseline: 7.4179x; 1.1414x over previous
//
#include <hip/hip_runtime.h>

constexpr int NN = 50000;          // nodes
constexpr int NE = 800000;         // edges
constexpr int C1 = 128;            // in/hidden channels
constexpr int C2 = 64;             // out channels
constexpr int NB = (NN + 255) / 256;   // 196 scan blocks

// float -> bf16 with round-to-nearest-even
__device__ __forceinline__ unsigned short f2bf(float f) {
    unsigned int u = __float_as_uint(f);
    u += 0x7FFFu + ((u >> 16) & 1u);
    return (unsigned short)(u >> 16);
}
// packed bf16 pair -> two floats (low ushort = even element, high = odd)
__device__ __forceinline__ float2 bf2f(unsigned int u) {
    return make_float2(__uint_as_float(u << 16), __uint_as_float(u & 0xFFFF0000u));
}

// ---------------- CSR build: histogram by dst ----------------
__global__ void hist_kernel(const int* __restrict__ dst, int* __restrict__ cnt) {
    int e = blockIdx.x * 256 + threadIdx.x;
    if (e < NE) atomicAdd(&cnt[dst[e]], 1);
}

// per-block exclusive scan of cnt -> off, block totals -> bsum
__global__ void scan1_kernel(const int* __restrict__ cnt, int* __restrict__ off,
                             int* __restrict__ bsum) {
    __shared__ int s[256];
    int i = blockIdx.x * 256 + threadIdx.x;
    int v = (i < NN) ? cnt[i] : 0;
    s[threadIdx.x] = v;
    __syncthreads();
    #pragma unroll
    for (int d = 1; d < 256; d <<= 1) {
        int t = (threadIdx.x >= d) ? s[threadIdx.x - d] : 0;
        __syncthreads();
        s[threadIdx.x] += t;
        __syncthreads();
    }
    if (i < NN) off[i] = s[threadIdx.x] - v;   // exclusive
    if (threadIdx.x == 255) bsum[blockIdx.x] = s[255];
}

// exclusive scan of the block sums — one 256-thread block, LDS scan
__global__ void scan2_kernel(int* __restrict__ bsum) {
    __shared__ int s[256];
    int t = threadIdx.x;
    int v = (t < NB) ? bsum[t] : 0;
    s[t] = v;
    __syncthreads();
    #pragma unroll
    for (int d = 1; d < 256; d <<= 1) {
        int u = (t >= d) ? s[t - d] : 0;
        __syncthreads();
        s[t] += u;
        __syncthreads();
    }
    if (t < NB) bsum[t] = s[t] - v;   // exclusive
}

// add block offsets; init cursor; dinv = rsqrt(deg+1)
__global__ void scan3_kernel(const int* __restrict__ cnt, int* __restrict__ off,
                             const int* __restrict__ bsum, int* __restrict__ cursor,
                             float* __restrict__ dinv) {
    int i = blockIdx.x * 256 + threadIdx.x;
    if (i < NN) {
        int o = off[i] + bsum[blockIdx.x];
        off[i] = o;
        cursor[i] = o;
        dinv[i] = rsqrtf((float)cnt[i] + 1.0f);
    }
}

// placement scatter: esrc[pos] = src  (pos via int atomic on cursor)
__global__ void build_kernel(const int* __restrict__ src, const int* __restrict__ dst,
                             int* __restrict__ cursor, int* __restrict__ esrc) {
    int e = blockIdx.x * 256 + threadIdx.x;
    if (e < NE) {
        int pos = atomicAdd(&cursor[dst[e]], 1);
        esrc[pos] = src[e];
    }
}

// ---------------- matmul 1: g1(bf16) = dinv * (x @ W1), x[N,128], W1[128,128] ----------------
__global__ __launch_bounds__(256) void mm1_kernel(const float* __restrict__ x,
                                                  const float* __restrict__ W,
                                                  const float* __restrict__ dinv,
                                                  unsigned short* __restrict__ g1) {
    __shared__ float xs[32][128];
    __shared__ float Wl[64][128];
    const int t = threadIdx.x;
    const int row0 = blockIdx.x * 32;

    #pragma unroll
    for (int i = 0; i < 4; i++) {
        int fi = t + i * 256;
        int r = fi >> 5;
        int c4 = fi & 31;
        int row = row0 + r;
        float4 v = (row < NN) ? ((const float4*)x)[(size_t)row * 32 + c4]
                              : make_float4(0.f, 0.f, 0.f, 0.f);
        *(float4*)&xs[r][c4 * 4] = v;
    }

    float acc[4][4];
    #pragma unroll
    for (int a = 0; a < 4; a++)
        #pragma unroll
        for (int b = 0; b < 4; b++) acc[a][b] = 0.f;

    const int cg = t & 31;
    const int rsub = t >> 5;

    for (int kh = 0; kh < 2; kh++) {
        __syncthreads();
        #pragma unroll
        for (int i = 0; i < 8; i++) {
            int fi = t + i * 256;
            int kk = fi >> 5;
            int cc = fi & 31;
            ((float4*)&Wl[kk][0])[cc] = ((const float4*)W)[(size_t)(kh * 64 + kk) * 32 + cc];
        }
        __syncthreads();
        #pragma unroll
        for (int rt = 0; rt < 4; rt++) {
            int r = rt * 8 + rsub;
            #pragma unroll 8
            for (int k = 0; k < 64; k++) {
                float xv = xs[r][kh * 64 + k];
                float4 wv = *(const float4*)&Wl[k][cg * 4];
                acc[rt][0] += xv * wv.x;
                acc[rt][1] += xv * wv.y;
                acc[rt][2] += xv * wv.z;
                acc[rt][3] += xv * wv.w;
            }
        }
    }

    #pragma unroll
    for (int rt = 0; rt < 4; rt++) {
        int row = row0 + rt * 8 + rsub;
        if (row < NN) {
            float s = dinv[row];
            ushort4 o;
            o.x = f2bf(acc[rt][0] * s);
            o.y = f2bf(acc[rt][1] * s);
            o.z = f2bf(acc[rt][2] * s);
            o.w = f2bf(acc[rt][3] * s);
            ((ushort4*)(g1 + (size_t)row * C1))[cg] = o;
        }
    }
}

// ---------------- matmul 2: g2(bf16) = dinv * (x2 @ W2), x2[N,128], W2[128,64] ----------------
__global__ __launch_bounds__(256) void mm2_kernel(const float* __restrict__ x2,
                                                  const float* __restrict__ W,
                                                  const float* __restrict__ dinv,
                                                  unsigned short* __restrict__ g2) {
    __shared__ float xs[32][132];
    __shared__ float Wl[128][64];
    const int t = threadIdx.x;
    const int row0 = blockIdx.x * 32;

    #pragma unroll
    for (int i = 0; i < 8; i++) {
        int fi = t + i * 256;
        ((float4*)Wl)[fi] = ((const float4*)W)[fi];
    }
    #pragma unroll
    for (int i = 0; i < 4; i++) {
        int fi = t + i * 256;
        int r = fi >> 5;
        int c4 = fi & 31;
        int row = row0 + r;
        float4 v = (row < NN) ? ((const float4*)x2)[(size_t)row * 32 + c4]
                              : make_float4(0.f, 0.f, 0.f, 0.f);
        *(float4*)&xs[r][c4 * 4] = v;
    }
    __syncthreads();

    const int cg = t & 15;
    const int rsub = t >> 4;
    float acc[2][4];
    #pragma unroll
    for (int a = 0; a < 2; a++)
        #pragma unroll
        for (int b = 0; b < 4; b++) acc[a][b] = 0.f;

    #pragma unroll
    for (int rt = 0; rt < 2; rt++) {
        int r = rt * 16 + rsub;
        #pragma unroll 8
        for (int k = 0; k < 128; k++) {
            float xv = xs[r][k];
            float4 wv = *(const float4*)&Wl[k][cg * 4];
            acc[rt][0] += xv * wv.x;
            acc[rt][1] += xv * wv.y;
            acc[rt][2] += xv * wv.z;
            acc[rt][3] += xv * wv.w;
        }
    }
    #pragma unroll
    for (int rt = 0; rt < 2; rt++) {
        int row = row0 + rt * 16 + rsub;
        if (row < NN) {
            float s = dinv[row];
            ushort4 o;
            o.x = f2bf(acc[rt][0] * s);
            o.y = f2bf(acc[rt][1] * s);
            o.z = f2bf(acc[rt][2] * s);
            o.w = f2bf(acc[rt][3] * s);
            ((ushort4*)(g2 + (size_t)row * C2))[cg] = o;
        }
    }
}

// ---------------- gather layer 1: one wave per node, bf16 rows (256 B), fp32 accum ----------------
// x2[n] = relu(dinv[n] * (g1[n] + sum_{s in N(n)} g1[s]) + b1)
__global__ __launch_bounds__(256) void gather1_kernel(const unsigned int* __restrict__ g1,
                                                      const int* __restrict__ esrc,
                                                      const int* __restrict__ off,
                                                      const int* __restrict__ cnt,
                                                      const float* __restrict__ dinv,
                                                      const float* __restrict__ b1,
                                                      float* __restrict__ x2) {
    int wave = threadIdx.x >> 6;
    int lane = threadIdx.x & 63;
    int n = blockIdx.x * 4 + wave;
    if (n >= NN) return;
    float2 a0 = bf2f(g1[(size_t)n * 64 + lane]);   // self-loop term
    float2 a1 = make_float2(0.f, 0.f);
    float2 a2 = make_float2(0.f, 0.f);
    float2 a3 = make_float2(0.f, 0.f);
    int s0 = off[n];
    int e0 = s0 + cnt[n];
    int i = s0;
    for (; i + 3 < e0; i += 4) {
        int sa = esrc[i], sb = esrc[i + 1], sc = esrc[i + 2], sd = esrc[i + 3];
        float2 va = bf2f(g1[(size_t)sa * 64 + lane]);
        float2 vb = bf2f(g1[(size_t)sb * 64 + lane]);
        float2 vc = bf2f(g1[(size_t)sc * 64 + lane]);
        float2 vd = bf2f(g1[(size_t)sd * 64 + lane]);
        a0.x += va.x; a0.y += va.y;
        a1.x += vb.x; a1.y += vb.y;
        a2.x += vc.x; a2.y += vc.y;
        a3.x += vd.x; a3.y += vd.y;
    }
    for (; i < e0; i++) {
        float2 va = bf2f(g1[(size_t)esrc[i] * 64 + lane]);
        a0.x += va.x; a0.y += va.y;
    }
    a0.x += a1.x + a2.x + a3.x;
    a0.y += a1.y + a2.y + a3.y;
    float s = dinv[n];
    float2 bb = ((const float2*)b1)[lane];
    float2 o = make_float2(fmaxf(s * a0.x + bb.x, 0.f), fmaxf(s * a0.y + bb.y, 0.f));
    ((float2*)x2)[(size_t)n * 64 + lane] = o;
}

// ---------------- gather layer 2: half-wave per node, bf16 rows (128 B), fp32 accum ----------------
// out[n] = dinv[n] * (g2[n] + sum) + b2
__global__ __launch_bounds__(256) void gather2_kernel(const unsigned int* __restrict__ g2,
                                                      const int* __restrict__ esrc,
                                                      const int* __restrict__ off,
                                                      const int* __restrict__ cnt,
                                                      const float* __restrict__ dinv,
                                                      const float* __restrict__ b2,
                                                      float* __restrict__ out) {
    int lane = threadIdx.x & 31;                 // 32 lanes per node (row = 32 uints)
    int n = blockIdx.x * 8 + (threadIdx.x >> 5);
    if (n >= NN) return;
    float2 a0 = bf2f(g2[(size_t)n * 32 + lane]); // self-loop term
    float2 a1 = make_float2(0.f, 0.f);
    float2 a2 = make_float2(0.f, 0.f);
    float2 a3 = make_float2(0.f, 0.f);
    int s0 = off[n];
    int e0 = s0 + cnt[n];
    int i = s0;
    for (; i + 3 < e0; i += 4) {
        int sa = esrc[i], sb = esrc[i + 1], sc = esrc[i + 2], sd = esrc[i + 3];
        float2 va = bf2f(g2[(size_t)sa * 32 + lane]);
        float2 vb = bf2f(g2[(size_t)sb * 32 + lane]);
        float2 vc = bf2f(g2[(size_t)sc * 32 + lane]);
        float2 vd = bf2f(g2[(size_t)sd * 32 + lane]);
        a0.x += va.x; a0.y += va.y;
        a1.x += vb.x; a1.y += vb.y;
        a2.x += vc.x; a2.y += vc.y;
        a3.x += vd.x; a3.y += vd.y;
    }
    for (; i < e0; i++) {
        float2 va = bf2f(g2[(size_t)esrc[i] * 32 + lane]);
        a0.x += va.x; a0.y += va.y;
    }
    a0.x += a1.x + a2.x + a3.x;
    a0.y += a1.y + a2.y + a3.y;
    float s = dinv[n];
    float2 bb = ((const float2*)b2)[lane];
    ((float2*)out)[(size_t)n * 32 + lane] =
        make_float2(s * a0.x + bb.x, s * a0.y + bb.y);
}

extern "C" void kernel_launch(void* const* d_in, const int* in_sizes, int n_in,
                              void* d_out, int out_size, void* d_ws, size_t ws_size,
                              hipStream_t stream) {
    const float* x  = (const float*)d_in[0];
    const int* edges = (const int*)d_in[1];     // [2, NE] int32
    const float* W1 = (const float*)d_in[2];
    const float* b1 = (const float*)d_in[3];
    const float* W2 = (const float*)d_in[4];
    const float* b2 = (const float*)d_in[5];
    const int* src = edges;
    const int* dst = edges + NE;

    // workspace layout (all chunks 16B-aligned)
    int* cnt    = (int*)d_ws;                       // 50048
    int* off    = cnt + 50048;                      // 50048
    int* cursor = off + 50048;                      // 50048
    int* bsum   = cursor + 50048;                   // 256
    int* esrc   = bsum + 256;                       // 800000
    float* dinv = (float*)(esrc + NE);              // 50048
    unsigned short* g1 = (unsigned short*)(dinv + 50048);   // [N,128] bf16
    float* x2   = (float*)(g1 + (size_t)NN * C1);   // [N,128] fp32
    unsigned short* g2 = g1;                        // alias: g1 dead before mm2 runs
    float* out  = (float*)d_out;

    hipMemsetAsync(cnt, 0, (size_t)50048 * sizeof(int), stream);

    hist_kernel<<<(NE + 255) / 256, 256, 0, stream>>>(dst, cnt);
    scan1_kernel<<<NB, 256, 0, stream>>>(cnt, off, bsum);
    scan2_kernel<<<1, 256, 0, stream>>>(bsum);
    scan3_kernel<<<NB, 256, 0, stream>>>(cnt, off, bsum, cursor, dinv);
    build_kernel<<<(NE + 255) / 256, 256, 0, stream>>>(src, dst, cursor, esrc);

    mm1_kernel<<<(NN + 31) / 32, 256, 0, stream>>>(x, W1, dinv, g1);
    gather1_kernel<<<(NN + 3) / 4, 256, 0, stream>>>((const unsigned int*)g1, esrc, off, cnt,
                                                     dinv, b1, x2);

    mm2_kernel<<<(NN + 31) / 32, 256, 0, stream>>>(x2, W2, dinv, g2);
    gather2_kernel<<<(NN + 7) / 8, 256, 0, stream>>>((const unsigned int*)g2, esrc, off, cnt,
                                                     dinv, b2, out);
}

// Round 4
// 271.850 us; speedup vs baseline: 8.2448x; 1.1115x over previous
//
#include <hip/hip_runtime.h>

typedef __attribute__((ext_vector_type(8))) short bf16x8;
typedef __attribute__((ext_vector_type(4))) float f32x4;

constexpr int NN = 50000;          // nodes
constexpr int NE = 800000;         // edges
constexpr int C1 = 128;            // in/hidden channels
constexpr int C2 = 64;             // out channels
constexpr int NB = (NN + 255) / 256;   // 196 scan blocks
constexpr int MT = NN / 16;        // 3125 M-tiles (exact)
constexpr int MMWAVES = 512;       // 128 blocks * 4 waves

// float -> bf16 round-to-nearest-even
__device__ __forceinline__ unsigned short f2bf(float f) {
    unsigned int u = __float_as_uint(f);
    u += 0x7FFFu + ((u >> 16) & 1u);
    return (unsigned short)(u >> 16);
}
// packed bf16 pair -> two floats (low ushort = even element)
__device__ __forceinline__ float2 bf2f(unsigned int u) {
    return make_float2(__uint_as_float(u << 16), __uint_as_float(u & 0xFFFF0000u));
}
__device__ __forceinline__ bf16x8 pack8(float4 a, float4 b) {
    bf16x8 r;
    r[0] = (short)f2bf(a.x); r[1] = (short)f2bf(a.y);
    r[2] = (short)f2bf(a.z); r[3] = (short)f2bf(a.w);
    r[4] = (short)f2bf(b.x); r[5] = (short)f2bf(b.y);
    r[6] = (short)f2bf(b.z); r[7] = (short)f2bf(b.w);
    return r;
}

// ---------------- CSR build: histogram by dst ----------------
__global__ void hist_kernel(const int* __restrict__ dst, int* __restrict__ cnt) {
    int e = blockIdx.x * 256 + threadIdx.x;
    if (e < NE) atomicAdd(&cnt[dst[e]], 1);
}

__global__ void scan1_kernel(const int* __restrict__ cnt, int* __restrict__ off,
                             int* __restrict__ bsum) {
    __shared__ int s[256];
    int i = blockIdx.x * 256 + threadIdx.x;
    int v = (i < NN) ? cnt[i] : 0;
    s[threadIdx.x] = v;
    __syncthreads();
    #pragma unroll
    for (int d = 1; d < 256; d <<= 1) {
        int t = (threadIdx.x >= d) ? s[threadIdx.x - d] : 0;
        __syncthreads();
        s[threadIdx.x] += t;
        __syncthreads();
    }
    if (i < NN) off[i] = s[threadIdx.x] - v;   // exclusive
    if (threadIdx.x == 255) bsum[blockIdx.x] = s[255];
}

__global__ void scan2_kernel(int* __restrict__ bsum) {
    __shared__ int s[256];
    int t = threadIdx.x;
    int v = (t < NB) ? bsum[t] : 0;
    s[t] = v;
    __syncthreads();
    #pragma unroll
    for (int d = 1; d < 256; d <<= 1) {
        int u = (t >= d) ? s[t - d] : 0;
        __syncthreads();
        s[t] += u;
        __syncthreads();
    }
    if (t < NB) bsum[t] = s[t] - v;   // exclusive
}

__global__ void scan3_kernel(const int* __restrict__ cnt, int* __restrict__ off,
                             const int* __restrict__ bsum, int* __restrict__ cursor,
                             float* __restrict__ dinv) {
    int i = blockIdx.x * 256 + threadIdx.x;
    if (i < NN) {
        int o = off[i] + bsum[blockIdx.x];
        off[i] = o;
        cursor[i] = o;
        dinv[i] = rsqrtf((float)cnt[i] + 1.0f);
    }
}

__global__ void build_kernel(const int* __restrict__ src, const int* __restrict__ dst,
                             int* __restrict__ cursor, int* __restrict__ esrc) {
    int e = blockIdx.x * 256 + threadIdx.x;
    if (e < NE) {
        int pos = atomicAdd(&cursor[dst[e]], 1);
        esrc[pos] = src[e];
    }
}

// ---------------- mm1: g1(bf16) = dinv * (x @ W1) via MFMA 16x16x32 bf16 ----------------
// LDS holds W1 pre-permuted to B-fragment order: [kstep][ntile][lane][j]
// B[k][n]: lane = quad*16 + (n&15), k = kstep*32 + quad*8 + j
__global__ __launch_bounds__(256, 2) void mm1_kernel(const float* __restrict__ x,
                                                     const float* __restrict__ W,
                                                     const float* __restrict__ dinv,
                                                     unsigned short* __restrict__ g1) {
    __shared__ unsigned short wl[4][8][64][8];   // 32 KB
    const int t = threadIdx.x;
    for (int i = 0; i < 64; i++) {
        int idx = i * 256 + t;          // 16384 = 64*256
        int k = idx >> 7, n = idx & 127;
        wl[k >> 5][n >> 4][((k >> 3) & 3) * 16 + (n & 15)][k & 7] = f2bf(W[idx]);
    }
    __syncthreads();
    const int lane = t & 63, lm = lane & 15, quad = lane >> 4;

    bf16x8 bfr[4][8];                   // all of W1 as fragments: 128 VGPRs
    #pragma unroll
    for (int s = 0; s < 4; s++)
        #pragma unroll
        for (int nt = 0; nt < 8; nt++)
            bfr[s][nt] = *(const bf16x8*)&wl[s][nt][lane][0];

    int wg = blockIdx.x * 4 + (t >> 6);
    for (int tile = wg; tile < MT; tile += MMWAVES) {
        int row0 = tile << 4;
        const float* xr = x + (size_t)(row0 + lm) * 128 + quad * 8;
        bf16x8 af[4];
        #pragma unroll
        for (int s = 0; s < 4; s++) {
            float4 p = *(const float4*)(xr + s * 32);
            float4 q = *(const float4*)(xr + s * 32 + 4);
            af[s] = pack8(p, q);
        }
        f32x4 acc[8];
        #pragma unroll
        for (int nt = 0; nt < 8; nt++) acc[nt] = (f32x4){0.f, 0.f, 0.f, 0.f};
        #pragma unroll
        for (int s = 0; s < 4; s++)
            #pragma unroll
            for (int nt = 0; nt < 8; nt++)
                acc[nt] = __builtin_amdgcn_mfma_f32_16x16x32_bf16(af[s], bfr[s][nt],
                                                                  acc[nt], 0, 0, 0);
        float4 dv = *(const float4*)(dinv + row0 + quad * 4);
        float dvv[4] = {dv.x, dv.y, dv.z, dv.w};
        #pragma unroll
        for (int nt = 0; nt < 8; nt++)
            #pragma unroll
            for (int r = 0; r < 4; r++)
                g1[(size_t)(row0 + quad * 4 + r) * 128 + nt * 16 + lm] =
                    f2bf(acc[nt][r] * dvv[r]);
    }
}

// ---------------- mm2: g2(bf16) = dinv * (x2 @ W2), x2 already bf16 ----------------
__global__ __launch_bounds__(256, 2) void mm2_kernel(const unsigned short* __restrict__ x2,
                                                     const float* __restrict__ W,
                                                     const float* __restrict__ dinv,
                                                     unsigned short* __restrict__ g2) {
    __shared__ unsigned short wl[4][4][64][8];   // 16 KB
    const int t = threadIdx.x;
    for (int i = 0; i < 32; i++) {
        int idx = i * 256 + t;          // 8192 = 32*256
        int k = idx >> 6, n = idx & 63;
        wl[k >> 5][n >> 4][((k >> 3) & 3) * 16 + (n & 15)][k & 7] = f2bf(W[idx]);
    }
    __syncthreads();
    const int lane = t & 63, lm = lane & 15, quad = lane >> 4;

    bf16x8 bfr[4][4];
    #pragma unroll
    for (int s = 0; s < 4; s++)
        #pragma unroll
        for (int nt = 0; nt < 4; nt++)
            bfr[s][nt] = *(const bf16x8*)&wl[s][nt][lane][0];

    int wg = blockIdx.x * 4 + (t >> 6);
    for (int tile = wg; tile < MT; tile += MMWAVES) {
        int row0 = tile << 4;
        const bf16x8* xr = (const bf16x8*)(x2 + (size_t)(row0 + lm) * 128 + quad * 8);
        bf16x8 af[4];
        #pragma unroll
        for (int s = 0; s < 4; s++) af[s] = xr[s * 4];   // kstep stride = 32 ushorts
        f32x4 acc[4];
        #pragma unroll
        for (int nt = 0; nt < 4; nt++) acc[nt] = (f32x4){0.f, 0.f, 0.f, 0.f};
        #pragma unroll
        for (int s = 0; s < 4; s++)
            #pragma unroll
            for (int nt = 0; nt < 4; nt++)
                acc[nt] = __builtin_amdgcn_mfma_f32_16x16x32_bf16(af[s], bfr[s][nt],
                                                                  acc[nt], 0, 0, 0);
        float4 dv = *(const float4*)(dinv + row0 + quad * 4);
        float dvv[4] = {dv.x, dv.y, dv.z, dv.w};
        #pragma unroll
        for (int nt = 0; nt < 4; nt++)
            #pragma unroll
            for (int r = 0; r < 4; r++)
                g2[(size_t)(row0 + quad * 4 + r) * 64 + nt * 16 + lm] =
                    f2bf(acc[nt][r] * dvv[r]);
    }
}

// ---------------- gather layer 1: one wave per node; bf16 in, bf16 out ----------------
// x2[n] = relu(dinv[n] * (g1[n] + sum_{s in N(n)} g1[s]) + b1)   [bf16 packed]
__global__ __launch_bounds__(256) void gather1_kernel(const unsigned int* __restrict__ g1,
                                                      const int* __restrict__ esrc,
                                                      const int* __restrict__ off,
                                                      const int* __restrict__ cnt,
                                                      const float* __restrict__ dinv,
                                                      const float* __restrict__ b1,
                                                      unsigned int* __restrict__ x2) {
    int wave = threadIdx.x >> 6;
    int lane = threadIdx.x & 63;
    int n = blockIdx.x * 4 + wave;
    if (n >= NN) return;
    float2 a0 = bf2f(g1[(size_t)n * 64 + lane]);   // self-loop term
    float2 a1 = make_float2(0.f, 0.f);
    float2 a2 = make_float2(0.f, 0.f);
    float2 a3 = make_float2(0.f, 0.f);
    int s0 = off[n];
    int e0 = s0 + cnt[n];
    int i = s0;
    for (; i + 3 < e0; i += 4) {
        int sa = esrc[i], sb = esrc[i + 1], sc = esrc[i + 2], sd = esrc[i + 3];
        float2 va = bf2f(g1[(size_t)sa * 64 + lane]);
        float2 vb = bf2f(g1[(size_t)sb * 64 + lane]);
        float2 vc = bf2f(g1[(size_t)sc * 64 + lane]);
        float2 vd = bf2f(g1[(size_t)sd * 64 + lane]);
        a0.x += va.x; a0.y += va.y;
        a1.x += vb.x; a1.y += vb.y;
        a2.x += vc.x; a2.y += vc.y;
        a3.x += vd.x; a3.y += vd.y;
    }
    for (; i < e0; i++) {
        float2 va = bf2f(g1[(size_t)esrc[i] * 64 + lane]);
        a0.x += va.x; a0.y += va.y;
    }
    a0.x += a1.x + a2.x + a3.x;
    a0.y += a1.y + a2.y + a3.y;
    float s = dinv[n];
    float2 bb = ((const float2*)b1)[lane];
    float ox = fmaxf(s * a0.x + bb.x, 0.f);
    float oy = fmaxf(s * a0.y + bb.y, 0.f);
    x2[(size_t)n * 64 + lane] = ((unsigned int)f2bf(oy) << 16) | f2bf(ox);
}

// ---------------- gather layer 2: half-wave per node ----------------
// out[n] = dinv[n] * (g2[n] + sum) + b2   [fp32 out]
__global__ __launch_bounds__(256) void gather2_kernel(const unsigned int* __restrict__ g2,
                                                      const int* __restrict__ esrc,
                                                      const int* __restrict__ off,
                                                      const int* __restrict__ cnt,
                                                      const float* __restrict__ dinv,
                                                      const float* __restrict__ b2,
                                                      float* __restrict__ out) {
    int lane = threadIdx.x & 31;
    int n = blockIdx.x * 8 + (threadIdx.x >> 5);
    if (n >= NN) return;
    float2 a0 = bf2f(g2[(size_t)n * 32 + lane]);
    float2 a1 = make_float2(0.f, 0.f);
    float2 a2 = make_float2(0.f, 0.f);
    float2 a3 = make_float2(0.f, 0.f);
    int s0 = off[n];
    int e0 = s0 + cnt[n];
    int i = s0;
    for (; i + 3 < e0; i += 4) {
        int sa = esrc[i], sb = esrc[i + 1], sc = esrc[i + 2], sd = esrc[i + 3];
        float2 va = bf2f(g2[(size_t)sa * 32 + lane]);
        float2 vb = bf2f(g2[(size_t)sb * 32 + lane]);
        float2 vc = bf2f(g2[(size_t)sc * 32 + lane]);
        float2 vd = bf2f(g2[(size_t)sd * 32 + lane]);
        a0.x += va.x; a0.y += va.y;
        a1.x += vb.x; a1.y += vb.y;
        a2.x += vc.x; a2.y += vc.y;
        a3.x += vd.x; a3.y += vd.y;
    }
    for (; i < e0; i++) {
        float2 va = bf2f(g2[(size_t)esrc[i] * 32 + lane]);
        a0.x += va.x; a0.y += va.y;
    }
    a0.x += a1.x + a2.x + a3.x;
    a0.y += a1.y + a2.y + a3.y;
    float s = dinv[n];
    float2 bb = ((const float2*)b2)[lane];
    ((float2*)out)[(size_t)n * 32 + lane] =
        make_float2(s * a0.x + bb.x, s * a0.y + bb.y);
}

extern "C" void kernel_launch(void* const* d_in, const int* in_sizes, int n_in,
                              void* d_out, int out_size, void* d_ws, size_t ws_size,
                              hipStream_t stream) {
    const float* x  = (const float*)d_in[0];
    const int* edges = (const int*)d_in[1];     // [2, NE] int32
    const float* W1 = (const float*)d_in[2];
    const float* b1 = (const float*)d_in[3];
    const float* W2 = (const float*)d_in[4];
    const float* b2 = (const float*)d_in[5];
    const int* src = edges;
    const int* dst = edges + NE;

    // workspace layout (all chunks 16B-aligned)
    int* cnt    = (int*)d_ws;                       // 50048
    int* off    = cnt + 50048;                      // 50048
    int* cursor = off + 50048;                      // 50048
    int* bsum   = cursor + 50048;                   // 256
    int* esrc   = bsum + 256;                       // 800000
    float* dinv = (float*)(esrc + NE);              // 50048
    unsigned short* g1 = (unsigned short*)(dinv + 50048);   // [N,128] bf16
    unsigned short* x2 = g1 + (size_t)NN * C1;              // [N,128] bf16
    unsigned short* g2 = g1;                        // alias: g1 dead before mm2
    float* out  = (float*)d_out;

    hipMemsetAsync(cnt, 0, (size_t)50048 * sizeof(int), stream);

    hist_kernel<<<(NE + 255) / 256, 256, 0, stream>>>(dst, cnt);
    scan1_kernel<<<NB, 256, 0, stream>>>(cnt, off, bsum);
    scan2_kernel<<<1, 256, 0, stream>>>(bsum);
    scan3_kernel<<<NB, 256, 0, stream>>>(cnt, off, bsum, cursor, dinv);
    build_kernel<<<(NE + 255) / 256, 256, 0, stream>>>(src, dst, cursor, esrc);

    mm1_kernel<<<128, 256, 0, stream>>>(x, W1, dinv, g1);
    gather1_kernel<<<(NN + 3) / 4, 256, 0, stream>>>((const unsigned int*)g1, esrc, off, cnt,
                                                     dinv, b1, (unsigned int*)x2);

    mm2_kernel<<<128, 256, 0, stream>>>(x2, W2, dinv, g2);
    gather2_kernel<<<(NN + 7) / 8, 256, 0, stream>>>((const unsigned int*)g2, esrc, off, cnt,
                                                     dinv, b2, out);
}

// Round 5
// 211.631 us; speedup vs baseline: 10.5908x; 1.2845x over previous
//
#include <hip/hip_runtime.h>

typedef __attribute__((ext_vector_type(8))) short bf16x8;
typedef __attribute__((ext_vector_type(4))) float f32x4;

constexpr int NN = 50000;          // nodes
constexpr int NE = 800000;         // edges
constexpr int C1 = 128;            // in/hidden channels
constexpr int C2 = 64;             // out channels
constexpr int NBK = 196;           // dst buckets of 256 nodes (ceil(50000/256))
constexpr int EPB = 2048;          // edges per bin block (256 thr * 8)
constexpr int NBLK = (NE + EPB - 1) / EPB;   // 391
constexpr int MT = NN / 16;        // 3125 M-tiles (exact)
constexpr int MMB = 250;           // matmul blocks
constexpr int MMWAVES = MMB * 4;   // 1000 waves

// float -> bf16 round-to-nearest-even
__device__ __forceinline__ unsigned short f2bf(float f) {
    unsigned int u = __float_as_uint(f);
    u += 0x7FFFu + ((u >> 16) & 1u);
    return (unsigned short)(u >> 16);
}
// packed bf16 pair -> two floats (low ushort = even element)
__device__ __forceinline__ float2 bf2f(unsigned int u) {
    return make_float2(__uint_as_float(u << 16), __uint_as_float(u & 0xFFFF0000u));
}
__device__ __forceinline__ bf16x8 pack8(float4 a, float4 b) {
    bf16x8 r;
    r[0] = (short)f2bf(a.x); r[1] = (short)f2bf(a.y);
    r[2] = (short)f2bf(a.z); r[3] = (short)f2bf(a.w);
    r[4] = (short)f2bf(b.x); r[5] = (short)f2bf(b.y);
    r[6] = (short)f2bf(b.z); r[7] = (short)f2bf(b.w);
    return r;
}

// ---------------- CSR build pass 1: per-block counting sort by coarse bucket ----------------
// Packs edge as (dstLow<<16)|src (src<65536, dstLow=dst&255). Writes block-sorted chunk
// coalesced to ebuf[blk*EPB..], per-block bucket offsets to localOff[blk][0..196],
// and accumulates the global bucket histogram.
__global__ __launch_bounds__(256) void bin_kernel(const int* __restrict__ src,
                                                  const int* __restrict__ dst,
                                                  unsigned int* __restrict__ ebuf,
                                                  int* __restrict__ localOff,
                                                  int* __restrict__ bktHist) {
    __shared__ int lhist[NBK];
    __shared__ int ls[256];
    __shared__ int lcur[NBK];
    __shared__ unsigned int lbuf[EPB];
    const int t = threadIdx.x;
    const int base = blockIdx.x * EPB;
    if (t < NBK) lhist[t] = 0;
    __syncthreads();
    int b[8]; unsigned int p[8];
    #pragma unroll
    for (int i = 0; i < 8; i++) {
        int e = base + i * 256 + t;
        if (e < NE) {
            int s = src[e], d = dst[e];
            b[i] = d >> 8;
            p[i] = ((unsigned int)(d & 255) << 16) | (unsigned int)s;
            atomicAdd(&lhist[b[i]], 1);
        } else b[i] = -1;
    }
    __syncthreads();
    int v = (t < NBK) ? lhist[t] : 0;
    ls[t] = v;
    __syncthreads();
    #pragma unroll
    for (int d = 1; d < 256; d <<= 1) {
        int u = (t >= d) ? ls[t - d] : 0;
        __syncthreads();
        ls[t] += u;
        __syncthreads();
    }
    if (t < NBK) {
        int ex = ls[t] - v;
        lcur[t] = ex;
        localOff[blockIdx.x * 200 + t] = ex;
        if (v > 0) atomicAdd(&bktHist[t], v);
    }
    if (t == NBK - 1) localOff[blockIdx.x * 200 + NBK] = ls[t];
    __syncthreads();
    #pragma unroll
    for (int i = 0; i < 8; i++) {
        if (b[i] >= 0) {
            int lp = atomicAdd(&lcur[b[i]], 1);
            lbuf[lp] = p[i];
        }
    }
    __syncthreads();
    #pragma unroll
    for (int i = 0; i < 8; i++)
        ebuf[base + i * 256 + t] = lbuf[i * 256 + t];   // tail garbage never read
}

// ---------------- CSR build pass 2: scan of 196 bucket totals ----------------
__global__ void scanC_kernel(const int* __restrict__ bktHist, int* __restrict__ bktOff) {
    __shared__ int ls[256];
    int t = threadIdx.x;
    int v = (t < NBK) ? bktHist[t] : 0;
    ls[t] = v;
    __syncthreads();
    #pragma unroll
    for (int d = 1; d < 256; d <<= 1) {
        int u = (t >= d) ? ls[t - d] : 0;
        __syncthreads();
        ls[t] += u;
        __syncthreads();
    }
    if (t < NBK) bktOff[t] = ls[t] - v;
    if (t == 0) bktOff[NBK] = NE;
}

// ---------------- CSR build pass 3: one block per bucket; LDS hist/scan/cursor ----------------
// Writes esrc (random 4B but within this block's private 16KB window -> one XCD's L2),
// plus cnt/off/dinv for the bucket's 256 nodes.
__global__ __launch_bounds__(256) void place_kernel(const unsigned int* __restrict__ ebuf,
                                                    const int* __restrict__ localOff,
                                                    const int* __restrict__ bktOff,
                                                    int* __restrict__ esrc,
                                                    int* __restrict__ cnt,
                                                    int* __restrict__ off,
                                                    float* __restrict__ dinv) {
    __shared__ int lhist[256];
    __shared__ int ls[256];
    __shared__ int lcur[256];
    const int t = threadIdx.x;
    const int bkt = blockIdx.x;
    const int node0 = bkt << 8;
    const int nnodes = min(256, NN - node0);
    lhist[t] = 0;
    __syncthreads();
    for (int j = t; j < NBLK; j += 256) {
        int s = localOff[j * 200 + bkt];
        int e = localOff[j * 200 + bkt + 1];
        const unsigned int* q = ebuf + j * EPB;
        for (int k = s; k < e; k++) atomicAdd(&lhist[q[k] >> 16], 1);
    }
    __syncthreads();
    int v = lhist[t];
    ls[t] = v;
    __syncthreads();
    #pragma unroll
    for (int d = 1; d < 256; d <<= 1) {
        int u = (t >= d) ? ls[t - d] : 0;
        __syncthreads();
        ls[t] += u;
        __syncthreads();
    }
    int ex = ls[t] - v;
    lcur[t] = ex;
    const int segBase = bktOff[bkt];
    if (t < nnodes) {
        cnt[node0 + t] = v;
        off[node0 + t] = segBase + ex;
        dinv[node0 + t] = rsqrtf((float)v + 1.0f);
    }
    __syncthreads();
    for (int j = t; j < NBLK; j += 256) {
        int s = localOff[j * 200 + bkt];
        int e = localOff[j * 200 + bkt + 1];
        const unsigned int* q = ebuf + j * EPB;
        for (int k = s; k < e; k++) {
            unsigned int pp = q[k];
            int lp = atomicAdd(&lcur[pp >> 16], 1);
            esrc[segBase + lp] = (int)(pp & 0xFFFFu);
        }
    }
}

// ---------------- mm1: g1(bf16) = dinv * (x @ W1) via MFMA 16x16x32 bf16 ----------------
__global__ __launch_bounds__(256, 2) void mm1_kernel(const float* __restrict__ x,
                                                     const float* __restrict__ W,
                                                     const float* __restrict__ dinv,
                                                     unsigned short* __restrict__ g1) {
    __shared__ unsigned short wl[4][8][64][8];   // 32 KB, B-fragment order
    const int t = threadIdx.x;
    for (int i = 0; i < 64; i++) {
        int idx = i * 256 + t;
        int k = idx >> 7, n = idx & 127;
        wl[k >> 5][n >> 4][((k >> 3) & 3) * 16 + (n & 15)][k & 7] = f2bf(W[idx]);
    }
    __syncthreads();
    const int lane = t & 63, lm = lane & 15, quad = lane >> 4;

    bf16x8 bfr[4][8];
    #pragma unroll
    for (int s = 0; s < 4; s++)
        #pragma unroll
        for (int nt = 0; nt < 8; nt++)
            bfr[s][nt] = *(const bf16x8*)&wl[s][nt][lane][0];

    int wg = blockIdx.x * 4 + (t >> 6);
    for (int tile = wg; tile < MT; tile += MMWAVES) {
        int row0 = tile << 4;
        const float* xr = x + (size_t)(row0 + lm) * 128 + quad * 8;
        bf16x8 af[4];
        #pragma unroll
        for (int s = 0; s < 4; s++) {
            float4 p = *(const float4*)(xr + s * 32);
            float4 q = *(const float4*)(xr + s * 32 + 4);
            af[s] = pack8(p, q);
        }
        f32x4 acc[8];
        #pragma unroll
        for (int nt = 0; nt < 8; nt++) acc[nt] = (f32x4){0.f, 0.f, 0.f, 0.f};
        #pragma unroll
        for (int s = 0; s < 4; s++)
            #pragma unroll
            for (int nt = 0; nt < 8; nt++)
                acc[nt] = __builtin_amdgcn_mfma_f32_16x16x32_bf16(af[s], bfr[s][nt],
                                                                  acc[nt], 0, 0, 0);
        float4 dv = *(const float4*)(dinv + row0 + quad * 4);
        float dvv[4] = {dv.x, dv.y, dv.z, dv.w};
        #pragma unroll
        for (int nt = 0; nt < 8; nt++)
            #pragma unroll
            for (int r = 0; r < 4; r++)
                g1[(size_t)(row0 + quad * 4 + r) * 128 + nt * 16 + lm] =
                    f2bf(acc[nt][r] * dvv[r]);
    }
}

// ---------------- mm2: g2(bf16) = dinv * (x2 @ W2), x2 already bf16 ----------------
__global__ __launch_bounds__(256, 2) void mm2_kernel(const unsigned short* __restrict__ x2,
                                                     const float* __restrict__ W,
                                                     const float* __restrict__ dinv,
                                                     unsigned short* __restrict__ g2) {
    __shared__ unsigned short wl[4][4][64][8];   // 16 KB
    const int t = threadIdx.x;
    for (int i = 0; i < 32; i++) {
        int idx = i * 256 + t;
        int k = idx >> 6, n = idx & 63;
        wl[k >> 5][n >> 4][((k >> 3) & 3) * 16 + (n & 15)][k & 7] = f2bf(W[idx]);
    }
    __syncthreads();
    const int lane = t & 63, lm = lane & 15, quad = lane >> 4;

    bf16x8 bfr[4][4];
    #pragma unroll
    for (int s = 0; s < 4; s++)
        #pragma unroll
        for (int nt = 0; nt < 4; nt++)
            bfr[s][nt] = *(const bf16x8*)&wl[s][nt][lane][0];

    int wg = blockIdx.x * 4 + (t >> 6);
    for (int tile = wg; tile < MT; tile += MMWAVES) {
        int row0 = tile << 4;
        const bf16x8* xr = (const bf16x8*)(x2 + (size_t)(row0 + lm) * 128 + quad * 8);
        bf16x8 af[4];
        #pragma unroll
        for (int s = 0; s < 4; s++) af[s] = xr[s * 4];
        f32x4 acc[4];
        #pragma unroll
        for (int nt = 0; nt < 4; nt++) acc[nt] = (f32x4){0.f, 0.f, 0.f, 0.f};
        #pragma unroll
        for (int s = 0; s < 4; s++)
            #pragma unroll
            for (int nt = 0; nt < 4; nt++)
                acc[nt] = __builtin_amdgcn_mfma_f32_16x16x32_bf16(af[s], bfr[s][nt],
                                                                  acc[nt], 0, 0, 0);
        float4 dv = *(const float4*)(dinv + row0 + quad * 4);
        float dvv[4] = {dv.x, dv.y, dv.z, dv.w};
        #pragma unroll
        for (int nt = 0; nt < 4; nt++)
            #pragma unroll
            for (int r = 0; r < 4; r++)
                g2[(size_t)(row0 + quad * 4 + r) * 64 + nt * 16 + lm] =
                    f2bf(acc[nt][r] * dvv[r]);
    }
}

// ---------------- gather layer 1: one wave per node; bf16 in, bf16 out ----------------
__global__ __launch_bounds__(256) void gather1_kernel(const unsigned int* __restrict__ g1,
                                                      const int* __restrict__ esrc,
                                                      const int* __restrict__ off,
                                                      const int* __restrict__ cnt,
                                                      const float* __restrict__ dinv,
                                                      const float* __restrict__ b1,
                                                      unsigned int* __restrict__ x2) {
    int wave = threadIdx.x >> 6;
    int lane = threadIdx.x & 63;
    int n = blockIdx.x * 4 + wave;
    if (n >= NN) return;
    float2 a0 = bf2f(g1[(size_t)n * 64 + lane]);   // self-loop term
    float2 a1 = make_float2(0.f, 0.f);
    float2 a2 = make_float2(0.f, 0.f);
    float2 a3 = make_float2(0.f, 0.f);
    int s0 = off[n];
    int e0 = s0 + cnt[n];
    int i = s0;
    for (; i + 3 < e0; i += 4) {
        int sa = esrc[i], sb = esrc[i + 1], sc = esrc[i + 2], sd = esrc[i + 3];
        float2 va = bf2f(g1[(size_t)sa * 64 + lane]);
        float2 vb = bf2f(g1[(size_t)sb * 64 + lane]);
        float2 vc = bf2f(g1[(size_t)sc * 64 + lane]);
        float2 vd = bf2f(g1[(size_t)sd * 64 + lane]);
        a0.x += va.x; a0.y += va.y;
        a1.x += vb.x; a1.y += vb.y;
        a2.x += vc.x; a2.y += vc.y;
        a3.x += vd.x; a3.y += vd.y;
    }
    for (; i < e0; i++) {
        float2 va = bf2f(g1[(size_t)esrc[i] * 64 + lane]);
        a0.x += va.x; a0.y += va.y;
    }
    a0.x += a1.x + a2.x + a3.x;
    a0.y += a1.y + a2.y + a3.y;
    float s = dinv[n];
    float2 bb = ((const float2*)b1)[lane];
    float ox = fmaxf(s * a0.x + bb.x, 0.f);
    float oy = fmaxf(s * a0.y + bb.y, 0.f);
    x2[(size_t)n * 64 + lane] = ((unsigned int)f2bf(oy) << 16) | f2bf(ox);
}

// ---------------- gather layer 2: half-wave per node ----------------
__global__ __launch_bounds__(256) void gather2_kernel(const unsigned int* __restrict__ g2,
                                                      const int* __restrict__ esrc,
                                                      const int* __restrict__ off,
                                                      const int* __restrict__ cnt,
                                                      const float* __restrict__ dinv,
                                                      const float* __restrict__ b2,
                                                      float* __restrict__ out) {
    int lane = threadIdx.x & 31;
    int n = blockIdx.x * 8 + (threadIdx.x >> 5);
    if (n >= NN) return;
    float2 a0 = bf2f(g2[(size_t)n * 32 + lane]);
    float2 a1 = make_float2(0.f, 0.f);
    float2 a2 = make_float2(0.f, 0.f);
    float2 a3 = make_float2(0.f, 0.f);
    int s0 = off[n];
    int e0 = s0 + cnt[n];
    int i = s0;
    for (; i + 3 < e0; i += 4) {
        int sa = esrc[i], sb = esrc[i + 1], sc = esrc[i + 2], sd = esrc[i + 3];
        float2 va = bf2f(g2[(size_t)sa * 32 + lane]);
        float2 vb = bf2f(g2[(size_t)sb * 32 + lane]);
        float2 vc = bf2f(g2[(size_t)sc * 32 + lane]);
        float2 vd = bf2f(g2[(size_t)sd * 32 + lane]);
        a0.x += va.x; a0.y += va.y;
        a1.x += vb.x; a1.y += vb.y;
        a2.x += vc.x; a2.y += vc.y;
        a3.x += vd.x; a3.y += vd.y;
    }
    for (; i < e0; i++) {
        float2 va = bf2f(g2[(size_t)esrc[i] * 32 + lane]);
        a0.x += va.x; a0.y += va.y;
    }
    a0.x += a1.x + a2.x + a3.x;
    a0.y += a1.y + a2.y + a3.y;
    float s = dinv[n];
    float2 bb = ((const float2*)b2)[lane];
    ((float2*)out)[(size_t)n * 32 + lane] =
        make_float2(s * a0.x + bb.x, s * a0.y + bb.y);
}

extern "C" void kernel_launch(void* const* d_in, const int* in_sizes, int n_in,
                              void* d_out, int out_size, void* d_ws, size_t ws_size,
                              hipStream_t stream) {
    const float* x  = (const float*)d_in[0];
    const int* edges = (const int*)d_in[1];     // [2, NE] int32
    const float* W1 = (const float*)d_in[2];
    const float* b1 = (const float*)d_in[3];
    const float* W2 = (const float*)d_in[4];
    const float* b2 = (const float*)d_in[5];
    const int* src = edges;
    const int* dst = edges + NE;

    // workspace layout (all chunks 16B-aligned)
    int* bktHist   = (int*)d_ws;                        // 200
    int* bktOff    = bktHist + 200;                     // 208 (197 used)
    int* localOff  = bktOff + 208;                      // NBLK*200 = 78200, pad 78208
    unsigned int* ebuf = (unsigned int*)(localOff + 78208);   // NBLK*EPB = 800768
    int* esrc      = (int*)(ebuf + (size_t)NBLK * EPB); // 800000
    int* cnt       = esrc + NE;                         // 50048
    int* off       = cnt + 50048;                       // 50048
    float* dinv    = (float*)(off + 50048);             // 50048
    unsigned short* g1 = (unsigned short*)(dinv + 50048);   // [N,128] bf16
    unsigned short* x2 = g1 + (size_t)NN * C1;              // [N,128] bf16
    unsigned short* g2 = g1;                            // alias: g1 dead before mm2
    float* out = (float*)d_out;

    hipMemsetAsync(bktHist, 0, 200 * sizeof(int), stream);

    bin_kernel<<<NBLK, 256, 0, stream>>>(src, dst, ebuf, localOff, bktHist);
    scanC_kernel<<<1, 256, 0, stream>>>(bktHist, bktOff);
    place_kernel<<<NBK, 256, 0, stream>>>(ebuf, localOff, bktOff, esrc, cnt, off, dinv);

    mm1_kernel<<<MMB, 256, 0, stream>>>(x, W1, dinv, g1);
    gather1_kernel<<<(NN + 3) / 4, 256, 0, stream>>>((const unsigned int*)g1, esrc, off, cnt,
                                                     dinv, b1, (unsigned int*)x2);

    mm2_kernel<<<MMB, 256, 0, stream>>>(x2, W2, dinv, g2);
    gather2_kernel<<<(NN + 7) / 8, 256, 0, stream>>>((const unsigned int*)g2, esrc, off, cnt,
                                                     dinv, b2, out);
}